// Round 7
// baseline (299.586 us; speedup 1.0000x reference)
//
#include <hip/hip_runtime.h>
#include <math.h>

typedef float     floatx4 __attribute__((ext_vector_type(4)));
typedef long long i64;
typedef long long i64x2 __attribute__((ext_vector_type(2)));
typedef unsigned long long u64;

#define NROWS 16384
#define KC    2048
#define DIM   512

// d_out element offsets (all float32): loss, q[8388608], perplexity, idx[16384]
#define OUT_Q_OFF    1
#define OUT_P_OFF    (1 + 8388608)
#define OUT_IDX_OFF  (1 + 8388608 + 1)
// xt (row-major x copy) lives in d_out at element 4: 16B-aligned, spans
// [4, 4+8388608) -- tail overlaps P/idx[0..1] which are written only AFTER
// k_main has consumed xt. q region is overwritten by k_qe after k_main.
#define XT_OFF       4

// ws byte offsets
#define WS_COUNTS 0          // int[2048]   (zeroed each call)
#define WS_LOSS   8192       // float       (zeroed each call)
#define WS_W2D    8448       // double[2048]
#define WS_W2F    24832      // float[2048]
#define WS_IDX3   33024      // int4[16384]          (256 KB)
#define WS_CAND   295168     // u64[16384*16]        (2 MB)
#define WS_WB     2392320    // uchar[2048*512] fp8 codebook (W*2048), pair-interleaved frags (1 MB)

// pack 8 floats -> 8 fp8 e4m3 bytes (RNE, saturating)
__device__ __forceinline__ i64 pk_fp8x8(float f0, float f1, float f2, float f3,
                                        float f4, float f5, float f6, float f7) {
  int lo = __builtin_amdgcn_cvt_pk_fp8_f32(f0, f1, 0, false);
  lo     = __builtin_amdgcn_cvt_pk_fp8_f32(f2, f3, lo, true);
  int hi = __builtin_amdgcn_cvt_pk_fp8_f32(f4, f5, 0, false);
  hi     = __builtin_amdgcn_cvt_pk_fp8_f32(f6, f7, hi, true);
  return (i64)(((u64)(unsigned int)hi << 32) | (unsigned int)lo);
}

// monotone pack: fp32 score -> ascending uint, low 11 bits replaced by code
__device__ __forceinline__ unsigned int packsc(float s, int code) {
  union { float f; unsigned int u; } v; v.f = s;
  unsigned int u = v.u;
  u = (u & 0x80000000u) ? ~u : (u | 0x80000000u);
  return (u & 0xFFFFF800u) | (unsigned int)code;
}

// monotone pack: fp64 score -> ascending u64, low 11 bits replaced by code.
__device__ __forceinline__ u64 packsc64(double s, int code) {
  union { double d; u64 u; } v; v.d = s;
  u64 u = v.u;
  u = (u & 0x8000000000000000ull) ? ~u : (u | 0x8000000000000000ull);
  return (u & ~(u64)0x7FF) | (u64)code;
}

__device__ __forceinline__ void ins3(unsigned int* t, unsigned int v) {
  if (v < t[2]) {
    t[2] = v;
    if (t[2] < t[1]) { unsigned int tmp = t[1]; t[1] = t[2]; t[2] = tmp; }
    if (t[1] < t[0]) { unsigned int tmp = t[0]; t[0] = t[1]; t[1] = tmp; }
  }
}

// ---------------- k_prep: w2 (fp64+fp32) AND fp8 pair-interleaved codebook.
// Superfrag g in [0,8) per 16-code tile c16 holds k-steps 2g,2g+1 (1024 B):
// lane l at byte l*16 has 8 B of kstep 2g then 8 B of kstep 2g+1.
__global__ __launch_bounds__(256) void k_prep(const float* __restrict__ W,
                                              double* __restrict__ w2d,
                                              float* __restrict__ w2f,
                                              unsigned char* __restrict__ Wb) {
  int wave = threadIdx.x >> 6;
  int lane = threadIdx.x & 63;
  int k = blockIdx.x * 4 + wave;
  const float4* row4 = (const float4*)(W + (size_t)k * DIM);
  float4 a = row4[2 * lane];
  float4 b = row4[2 * lane + 1];
  // this lane holds dims [8*lane, 8*lane+8) of code k:
  // kstep ks = lane>>2, q = lane&3; superfrag sf = ks>>1, half hb = ks&1.
  int c16 = k >> 4, l15 = k & 15;
  int ks = lane >> 2, qq = lane & 3;
  int sf = ks >> 1, hb = ks & 1;
  i64 v = pk_fp8x8(a.x * 2048.0f, a.y * 2048.0f, a.z * 2048.0f, a.w * 2048.0f,
                   b.x * 2048.0f, b.y * 2048.0f, b.z * 2048.0f, b.w * 2048.0f);
  *(i64*)(Wb + (size_t)(c16 * 8 + sf) * 1024 + (qq * 16 + l15) * 16 + hb * 8) = v;
  double acc = 0.0;
  acc += (double)a.x*a.x + (double)a.y*a.y + (double)a.z*a.z + (double)a.w*a.w;
  acc += (double)b.x*b.x + (double)b.y*b.y + (double)b.z*b.z + (double)b.w*b.w;
  for (int o = 32; o > 0; o >>= 1) acc += __shfl_down(acc, o);
  if (lane == 0) { w2d[k] = acc; w2f[k] = (float)acc; }
}

// ---------------- k_xt: LDS-tiled transpose x[B,D,T] -> xt[n][d] (row-major)
__global__ __launch_bounds__(256) void k_xt(const float* __restrict__ x,
                                            float* __restrict__ xt) {
  __shared__ float tile[64][73];
  const int tid = threadIdx.x;
  const int d0  = blockIdx.x * 64;
  const int nt0 = blockIdx.y * 64;
  const int b   = nt0 >> 8;
  const int t0  = nt0 & 255;
  #pragma unroll
  for (int i = 0; i < 16; ++i) {
    int u = tid + i * 256;
    int tl = u & 63, dl = u >> 6;
    tile[tl][dl] = x[(size_t)b * 131072 + (size_t)(d0 + dl) * 256 + t0 + tl];
  }
  __syncthreads();
  const int rg = tid >> 4, c = tid & 15;
  #pragma unroll
  for (int i = 0; i < 4; ++i) {
    int rl = i * 16 + rg;
    float4 v = { tile[rl][c * 4 + 0], tile[rl][c * 4 + 1],
                 tile[rl][c * 4 + 2], tile[rl][c * 4 + 3] };
    *(float4*)&xt[(size_t)(nt0 + rl) * 512 + d0 + c * 4] = v;
  }
}

// ---------------- k_main: block = (32 rows, half the codebook).
// fp8 MFMA streaming (16B ring loads) -> per-half top-8 -> fp64 refine.
__global__ __launch_bounds__(256, 4) void k_main(
    const float* __restrict__ xt, const float* __restrict__ W,
    const unsigned char* __restrict__ Wb,
    const float* __restrict__ w2f, const double* __restrict__ w2d,
    u64* __restrict__ cand)
{
  __shared__ unsigned int candU[32 * 192];   // 24 KB packed coarse candidates
  __shared__ unsigned int ps8[32][8][8];     // 8 KB partial top-8
  __shared__ int top8i[32][8];

  const int tid  = threadIdx.x;
  const int w    = tid >> 6;          // wave: owns 256 codes of this half
  const int lane = tid & 63;
  const int q    = lane >> 4;
  const int l15  = lane & 15;
  const int h    = blockIdx.x & 1;    // codebook half
  const int n0   = (blockIdx.x >> 1) * 32;

  // ---- Phase A: 32 rows -> fp8 A-fragments (coalesced float4 from xt)
  i64 af[2][16];
  {
    const float* xp = xt + (size_t)(n0 + l15) * 512 + q * 8;
    #pragma unroll
    for (int rs = 0; rs < 2; ++rs)
      #pragma unroll
      for (int s = 0; s < 16; ++s) {
        const float* p = xp + (size_t)rs * 16 * 512 + s * 32;
        float4 a = *(const float4*)p;
        float4 b = *(const float4*)(p + 4);
        af[rs][s] = pk_fp8x8(a.x, a.y, a.z, a.w, b.x, b.y, b.z, b.w);
      }
  }

  unsigned int ts[2][4][3];   // packed top-3 per (rowset, acc-reg)
  #pragma unroll
  for (int rs = 0; rs < 2; ++rs)
    #pragma unroll
    for (int i = 0; i < 4; ++i)
      #pragma unroll
      for (int j = 0; j < 3; ++j) ts[rs][i][j] = 0xFFFFFFFFu;

  // ---- Phase B: barrier-free GEMM, 16B ring loads over 128 superfrags
  {
    const unsigned char* base =
        Wb + (size_t)((h * 64 + w * 16) * 8) * 1024 + lane * 16;
    i64x2 ring[8];
    #pragma unroll
    for (int p = 0; p < 8; ++p)
      ring[p] = *(const i64x2*)(base + (size_t)p * 1024);

    for (int ct = 0; ct < 16; ++ct) {
      floatx4 acc0 = {0.f, 0.f, 0.f, 0.f};
      floatx4 acc1 = {0.f, 0.f, 0.f, 0.f};
      #pragma unroll
      for (int p = 0; p < 8; ++p) {
        int fi = ct * 8 + p;
        int nf = (fi + 8 < 128) ? (fi + 8) : 127;   // wave-uniform clamp
        i64x2 bfr = ring[p];
        ring[p] = *(const i64x2*)(base + (size_t)nf * 1024);
        acc0 = __builtin_amdgcn_mfma_f32_16x16x32_fp8_fp8(af[0][2*p],   bfr[0], acc0, 0, 0, 0);
        acc1 = __builtin_amdgcn_mfma_f32_16x16x32_fp8_fp8(af[1][2*p],   bfr[0], acc1, 0, 0, 0);
        acc0 = __builtin_amdgcn_mfma_f32_16x16x32_fp8_fp8(af[0][2*p+1], bfr[1], acc0, 0, 0, 0);
        acc1 = __builtin_amdgcn_mfma_f32_16x16x32_fp8_fp8(af[1][2*p+1], bfr[1], acc1, 0, 0, 0);
      }
      // B scaled by 2048 -> acc = 2048*dot; s = w2 - 2*dot = fma(-2/2048, acc, w2)
      int code = (h * 64 + w * 16 + ct) * 16 + l15;
      float w2 = w2f[code];
      #pragma unroll
      for (int i = 0; i < 4; ++i) {
        ins3(ts[0][i], packsc(fmaf(-0.0009765625f, acc0[i], w2), code));
        ins3(ts[1][i], packsc(fmaf(-0.0009765625f, acc1[i], w2), code));
      }
    }
  }

  // ---- Phase C: dump packed candidates, two-stage merge -> top-8 per row
  #pragma unroll
  for (int rs = 0; rs < 2; ++rs)
    #pragma unroll
    for (int i = 0; i < 4; ++i) {
      int row = rs * 16 + q * 4 + i;
      #pragma unroll
      for (int j = 0; j < 3; ++j)
        candU[row * 192 + w * 48 + l15 * 3 + j] = ts[rs][i][j];
    }
  __syncthreads();

  {
    int row = tid >> 3, sl = tid & 7;
    unsigned int s8[8];
    #pragma unroll
    for (int k = 0; k < 8; ++k) s8[k] = 0xFFFFFFFFu;
    for (int e = 0; e < 24; ++e) {
      unsigned int v = candU[row * 192 + sl * 24 + e];
      if (v < s8[7]) {
        s8[7] = v;
        #pragma unroll
        for (int k = 7; k >= 1; --k)
          if (s8[k] < s8[k - 1]) { unsigned int t = s8[k-1]; s8[k-1] = s8[k]; s8[k] = t; }
      }
    }
    #pragma unroll
    for (int k = 0; k < 8; ++k) ps8[row][sl][k] = s8[k];
  }
  __syncthreads();

  if (tid < 32) {
    unsigned int s8[8];
    #pragma unroll
    for (int k = 0; k < 8; ++k) s8[k] = 0xFFFFFFFFu;
    const unsigned int* src = &ps8[tid][0][0];
    for (int e = 0; e < 64; ++e) {
      unsigned int v = src[e];
      if (v < s8[7]) {
        s8[7] = v;
        #pragma unroll
        for (int k = 7; k >= 1; --k)
          if (s8[k] < s8[k - 1]) { unsigned int t = s8[k-1]; s8[k-1] = s8[k]; s8[k] = t; }
      }
    }
    #pragma unroll
    for (int k = 0; k < 8; ++k) top8i[tid][k] = (int)(s8[k] & 0x7FFu);
  }
  __syncthreads();

  // ---- Phase D: exact fp64 re-score (both streams contiguous dwordx4)
  {
    int rr = tid >> 3, j = tid & 7;
    int code = top8i[rr][j];
    const float4* wr4 = (const float4*)(W + (size_t)code * DIM);
    const float4* xr4 = (const float4*)(xt + (size_t)(n0 + rr) * 512);
    double d0 = 0.0, d1 = 0.0, d2 = 0.0, d3 = 0.0;
    #pragma unroll 4
    for (int d4 = 0; d4 < 128; ++d4) {
      float4 wv = wr4[d4];
      float4 xv = xr4[d4];
      d0 = fma((double)xv.x, (double)wv.x, d0);
      d1 = fma((double)xv.y, (double)wv.y, d1);
      d2 = fma((double)xv.z, (double)wv.z, d2);
      d3 = fma((double)xv.w, (double)wv.w, d3);
    }
    double s = w2d[code] - 2.0 * ((d0 + d1) + (d2 + d3));
    cand[(size_t)(n0 + rr) * 16 + h * 8 + j] = packsc64(s, code);
  }
}

// ---------------- k_merge: per row, merge 2x8 fp64-keyed candidates -> top-3
__global__ __launch_bounds__(256) void k_merge(
    const u64* __restrict__ cand, int4* __restrict__ idx3,
    int* __restrict__ counts, float* __restrict__ out)
{
  int n = blockIdx.x * 256 + threadIdx.x;
  const u64* cp = cand + (size_t)n * 16;
  u64 k0 = ~0ull, k1 = ~0ull, k2 = ~0ull;
  #pragma unroll
  for (int e = 0; e < 16; ++e) {
    u64 v = cp[e];
    if (v < k2) {
      k2 = v;
      if (k2 < k1) { u64 t = k1; k1 = k2; k2 = t; }
      if (k1 < k0) { u64 t = k0; k0 = k1; k1 = t; }
    }
  }
  int c0 = (int)(k0 & 0x7FF), c1 = (int)(k1 & 0x7FF), c2 = (int)(k2 & 0x7FF);
  idx3[n] = make_int4(c0, c1, c2, 0);
  out[OUT_IDX_OFF + n] = (float)c2;
  atomicAdd(&counts[c0], 1);
  atomicAdd(&counts[c1], 1);
  atomicAdd(&counts[c2], 1);
}

// ---------------- k_qe: quantize + straight-through + fused loss (16 rows/block)
// Reads ORIGINAL x (not xt -- this kernel overwrites the xt region with q).
__global__ __launch_bounds__(256) void k_qe(
    const float* __restrict__ x, const float* __restrict__ W,
    const int4* __restrict__ idx3, float* __restrict__ out,
    float* __restrict__ loss_acc)
{
  __shared__ float lred[4];
  const int tid = threadIdx.x;
  const int lane = tid & 63;
  const int n0 = blockIdx.x * 16;
  const int b  = n0 >> 8;
  const int t0 = n0 & 255;
  const int rr = tid & 15;
  const int g  = tid >> 4;             // 16 d-groups of 32 dims

  int4 ii = idx3[n0 + rr];
  const float4* w0 = (const float4*)(W + (size_t)ii.x * DIM);
  const float4* w1 = (const float4*)(W + (size_t)ii.y * DIM);
  const float4* w2 = (const float4*)(W + (size_t)ii.z * DIM);
  const float*  xr = x + (size_t)b * 131072 + t0 + rr;
  float* outq = out + OUT_Q_OFF + (size_t)b * 131072 + t0 + rr;
  float lsum = 0.0f;
  #pragma unroll
  for (int d4 = 0; d4 < 8; ++d4) {
    int idx4 = g * 8 + d4;
    float4 a0 = w0[idx4], a1 = w1[idx4], a2 = w2[idx4];
    float qv[4] = { (a0.x + a1.x + a2.x) * (1.0f/3.0f),
                    (a0.y + a1.y + a2.y) * (1.0f/3.0f),
                    (a0.z + a1.z + a2.z) * (1.0f/3.0f),
                    (a0.w + a1.w + a2.w) * (1.0f/3.0f) };
    #pragma unroll
    for (int e = 0; e < 4; ++e) {
      size_t off = (size_t)(idx4 * 4 + e) * 256;
      float xv = xr[off];
      float diff = qv[e] - xv;             // quantized - inp
      outq[off] = xv + diff;               // straight-through value
      lsum += diff * diff;
    }
  }
  for (int o = 32; o > 0; o >>= 1) lsum += __shfl_down(lsum, o);
  if (lane == 0) lred[tid >> 6] = lsum;
  __syncthreads();
  if (tid == 0)
    atomicAdd(loss_acc, (lred[0] + lred[1]) + (lred[2] + lred[3]));
}

// ---------------- k_final: loss + perplexity
__global__ __launch_bounds__(256) void k_final(
    const int* __restrict__ counts, const float* __restrict__ loss_acc,
    float* __restrict__ out)
{
  int tid = threadIdx.x;
  float ent = 0.0f;
  for (int k = tid; k < KC; k += 256) {
    float p = (float)counts[k] * (1.0f / 16384.0f);
    ent += p * logf(p + 1e-10f);
  }
  for (int o = 32; o > 0; o >>= 1) ent += __shfl_down(ent, o);
  __shared__ float ps[4];
  if ((tid & 63) == 0) ps[tid >> 6] = ent;
  __syncthreads();
  if (tid == 0) {
    float total = (ps[0] + ps[1]) + (ps[2] + ps[3]);
    out[0] = 1.25f * loss_acc[0] * (1.0f / 8388608.0f);  // q + 0.25*e latent
    out[OUT_P_OFF] = expf(-total);
  }
}

extern "C" void kernel_launch(void* const* d_in, const int* in_sizes, int n_in,
                              void* d_out, int out_size, void* d_ws, size_t ws_size,
                              hipStream_t stream) {
  const float* x = (const float*)d_in[0];
  const float* W = (const float*)d_in[1];
  float* out = (float*)d_out;
  char* ws = (char*)d_ws;
  int*           counts   = (int*)(ws + WS_COUNTS);
  float*         loss_acc = (float*)(ws + WS_LOSS);
  double*        w2d      = (double*)(ws + WS_W2D);
  float*         w2f      = (float*)(ws + WS_W2F);
  int4*          idx3     = (int4*)(ws + WS_IDX3);
  u64*           cand     = (u64*)(ws + WS_CAND);
  unsigned char* Wb       = (unsigned char*)(ws + WS_WB);
  float*         xt       = out + XT_OFF;     // scratch inside d_out (16B-aligned)

  hipMemsetAsync(ws, 0, 8448, stream);   // counts + loss accumulator
  k_prep<<<KC / 4, 256, 0, stream>>>(W, w2d, w2f, Wb);
  k_xt<<<dim3(DIM / 64, NROWS / 64), 256, 0, stream>>>(x, xt);
  k_main<<<NROWS / 32 * 2, 256, 0, stream>>>(xt, W, Wb, w2f, w2d, cand);
  k_merge<<<NROWS / 256, 256, 0, stream>>>(cand, idx3, counts, out);
  k_qe<<<NROWS / 16, 256, 0, stream>>>(x, W, idx3, out, loss_acc);
  k_final<<<1, 256, 0, stream>>>(counts, loss_acc, out);
}

// Round 8
// 271.146 us; speedup vs baseline: 1.1049x; 1.1049x over previous
//
#include <hip/hip_runtime.h>
#include <math.h>

typedef float     floatx4 __attribute__((ext_vector_type(4)));
typedef long long i64;
typedef long long i64x2 __attribute__((ext_vector_type(2)));
typedef unsigned long long u64;

#define NROWS 16384
#define KC    2048
#define DIM   512

// d_out element offsets (all float32): loss, q[8388608], perplexity, idx[16384]
#define OUT_Q_OFF    1
#define OUT_P_OFF    (1 + 8388608)
#define OUT_IDX_OFF  (1 + 8388608 + 1)
// xt (row-major x copy) in d_out at element 4 (16B-aligned). Consumed by
// k_score/k_refine; overwritten later by k_qe/k_merge/k_final.
#define XT_OFF       4

// ws byte offsets
#define WS_COUNTS 0          // int[2048]   (zeroed each call)
#define WS_LOSS   8192       // float       (zeroed each call)
#define WS_W2D    8448       // double[2048]
#define WS_W2F    24832      // float[2048]
#define WS_IDX3   33024      // int4[16384]        (256 KB)
#define WS_TOP8   295168     // int[16384*8]       (512 KB)
#define WS_CAND   819456     // u64[16384*8]       (1 MB)
#define WS_WB     2392320    // uchar[2048*512] fp8 codebook (W*2048), superfrag-ordered (1 MB)

// pack 8 floats -> 8 fp8 e4m3 bytes (RNE, saturating)
__device__ __forceinline__ i64 pk_fp8x8(float f0, float f1, float f2, float f3,
                                        float f4, float f5, float f6, float f7) {
  int lo = __builtin_amdgcn_cvt_pk_fp8_f32(f0, f1, 0, false);
  lo     = __builtin_amdgcn_cvt_pk_fp8_f32(f2, f3, lo, true);
  int hi = __builtin_amdgcn_cvt_pk_fp8_f32(f4, f5, 0, false);
  hi     = __builtin_amdgcn_cvt_pk_fp8_f32(f6, f7, hi, true);
  return (i64)(((u64)(unsigned int)hi << 32) | (unsigned int)lo);
}

// monotone pack: fp32 score -> ascending uint, low 11 bits replaced by code
__device__ __forceinline__ unsigned int packsc(float s, int code) {
  union { float f; unsigned int u; } v; v.f = s;
  unsigned int u = v.u;
  u = (u & 0x80000000u) ? ~u : (u | 0x80000000u);
  return (u & 0xFFFFF800u) | (unsigned int)code;
}

// monotone pack: fp64 score -> ascending u64, low 11 bits replaced by code.
__device__ __forceinline__ u64 packsc64(double s, int code) {
  union { double d; u64 u; } v; v.d = s;
  u64 u = v.u;
  u = (u & 0x8000000000000000ull) ? ~u : (u | 0x8000000000000000ull);
  return (u & ~(u64)0x7FF) | (u64)code;
}

__device__ __forceinline__ void ins3(unsigned int* t, unsigned int v) {
  if (v < t[2]) {
    t[2] = v;
    if (t[2] < t[1]) { unsigned int tmp = t[1]; t[1] = t[2]; t[2] = tmp; }
    if (t[1] < t[0]) { unsigned int tmp = t[0]; t[0] = t[1]; t[1] = tmp; }
  }
}

// ---------------- k_prep: w2 (fp64+fp32) AND fp8 superfrag-ordered codebook.
// Superfrag (c16, p) = 1024 B: lane (q*16+l15) byte l*16 holds 8 B of kstep 2p
// then 8 B of kstep 2p+1 for code c16*16+l15, dims ks*32+q*8..+8.
__global__ __launch_bounds__(256) void k_prep(const float* __restrict__ W,
                                              double* __restrict__ w2d,
                                              float* __restrict__ w2f,
                                              unsigned char* __restrict__ Wb) {
  int wave = threadIdx.x >> 6;
  int lane = threadIdx.x & 63;
  int k = blockIdx.x * 4 + wave;
  const float4* row4 = (const float4*)(W + (size_t)k * DIM);
  float4 a = row4[2 * lane];
  float4 b = row4[2 * lane + 1];
  int c16 = k >> 4, l15 = k & 15;
  int ks = lane >> 2, qq = lane & 3;     // this lane holds dims [8*lane, +8)
  int sf = ks >> 1, hb = ks & 1;
  i64 v = pk_fp8x8(a.x * 2048.0f, a.y * 2048.0f, a.z * 2048.0f, a.w * 2048.0f,
                   b.x * 2048.0f, b.y * 2048.0f, b.z * 2048.0f, b.w * 2048.0f);
  *(i64*)(Wb + (size_t)(c16 * 8 + sf) * 1024 + (qq * 16 + l15) * 16 + hb * 8) = v;
  double acc = 0.0;
  acc += (double)a.x*a.x + (double)a.y*a.y + (double)a.z*a.z + (double)a.w*a.w;
  acc += (double)b.x*b.x + (double)b.y*b.y + (double)b.z*b.z + (double)b.w*b.w;
  for (int o = 32; o > 0; o >>= 1) acc += __shfl_down(acc, o);
  if (lane == 0) { w2d[k] = acc; w2f[k] = (float)acc; }
}

// ---------------- k_xt: LDS-tiled transpose x[B,D,T] -> xt[n][d] (row-major)
__global__ __launch_bounds__(256) void k_xt(const float* __restrict__ x,
                                            float* __restrict__ xt) {
  __shared__ float tile[64][73];
  const int tid = threadIdx.x;
  const int d0  = blockIdx.x * 64;
  const int nt0 = blockIdx.y * 64;
  const int b   = nt0 >> 8;
  const int t0  = nt0 & 255;
  #pragma unroll
  for (int i = 0; i < 16; ++i) {
    int u = tid + i * 256;
    int tl = u & 63, dl = u >> 6;
    tile[tl][dl] = x[(size_t)b * 131072 + (size_t)(d0 + dl) * 256 + t0 + tl];
  }
  __syncthreads();
  const int rg = tid >> 4, c = tid & 15;
  #pragma unroll
  for (int i = 0; i < 4; ++i) {
    int rl = i * 16 + rg;
    float4 v = { tile[rl][c * 4 + 0], tile[rl][c * 4 + 1],
                 tile[rl][c * 4 + 2], tile[rl][c * 4 + 3] };
    *(float4*)&xt[(size_t)(nt0 + rl) * 512 + d0 + c * 4] = v;
  }
}

// ---------------- k_score: block = 32 rows x FULL codebook. A-fragments in
// LDS (bank-optimal), 8 acc tiles persistent in AGPRs, K outer loop.
// Emits per-row top-8 coarse candidate codes.
__global__ __launch_bounds__(256, 2) void k_score(
    const float* __restrict__ xt, const unsigned char* __restrict__ Wb,
    const float* __restrict__ w2f, int* __restrict__ top8g)
{
  // als: 32 rows x 528 B (A frags)  UNION  candU: 32*192 u32 (24576 B)
  __shared__ __align__(16) char smem[24576];
  __shared__ unsigned int ps8[32][8][8];     // 8 KB partial top-8
  unsigned int* candU = (unsigned int*)smem;

  const int tid  = threadIdx.x;
  const int w    = tid >> 6;          // wave: owns codes [w*512, w*512+512)
  const int lane = tid & 63;
  const int q    = lane >> 4;
  const int l15  = lane & 15;
  const int n0   = blockIdx.x * 32;

  // ---- Phase A: cooperative xt -> fp8 -> LDS (pair-interleaved, stride 528)
  #pragma unroll
  for (int ps = 0; ps < 4; ++ps) {
    int c   = ps * 256 + tid;          // 16-float chunk id over 32 rows
    int row = c >> 5;
    int k16 = (c & 31) * 16;
    const float4* src = (const float4*)(xt + (size_t)(n0 + row) * 512 + k16);
    float4 v0 = src[0], v1 = src[1], v2 = src[2], v3 = src[3];
    i64 lo = pk_fp8x8(v0.x, v0.y, v0.z, v0.w, v1.x, v1.y, v1.z, v1.w);
    i64 hi = pk_fp8x8(v2.x, v2.y, v2.z, v2.w, v3.x, v3.y, v3.z, v3.w);
    int p = k16 >> 6, hb = (k16 >> 5) & 1, q0 = (k16 & 31) >> 3;
    char* dst = smem + row * 528 + p * 64 + hb * 8;
    *(i64*)(dst + q0 * 16)       = lo;
    *(i64*)(dst + (q0 + 1) * 16) = hi;
  }
  __syncthreads();

  unsigned int ts[2][4][3];   // packed top-3 per (rowset, acc-reg)
  #pragma unroll
  for (int rs = 0; rs < 2; ++rs)
    #pragma unroll
    for (int i = 0; i < 4; ++i)
      #pragma unroll
      for (int j = 0; j < 3; ++j) ts[rs][i][j] = 0xFFFFFFFFu;

  // ---- Phase B: 4 passes of 8 persistent acc tiles; K (8 pairs) outer.
  const unsigned char* wbase = Wb + lane * 16;
  const char* arow0 = smem + l15 * 528 + q * 16;
  for (int P = 0; P < 4; ++P) {
    floatx4 acc[8][2];
    #pragma unroll
    for (int t = 0; t < 8; ++t) {
      floatx4 z = {0.f, 0.f, 0.f, 0.f};
      acc[t][0] = z; acc[t][1] = z;
    }
    const int fbase = (w * 32 + P * 8) * 8;   // superfrag base (c16*8)
    i64x2 buf[8];
    #pragma unroll
    for (int t = 0; t < 8; ++t)
      buf[t] = *(const i64x2*)(wbase + (size_t)(fbase + t * 8) * 1024);

    for (int p = 0; p < 8; ++p) {
      const char* ar = arow0 + p * 64;
      i64x2 a0 = *(const i64x2*)(ar);             // rowset 0
      i64x2 a1 = *(const i64x2*)(ar + 16 * 528);  // rowset 1
      int np = (p < 7) ? (p + 1) : 7;             // wave-uniform clamp
      #pragma unroll
      for (int t = 0; t < 8; ++t) {
        i64x2 b = buf[t];
        buf[t] = *(const i64x2*)(wbase + (size_t)(fbase + t * 8 + np) * 1024);
        acc[t][0] = __builtin_amdgcn_mfma_f32_16x16x32_fp8_fp8(a0[0], b[0], acc[t][0], 0, 0, 0);
        acc[t][0] = __builtin_amdgcn_mfma_f32_16x16x32_fp8_fp8(a0[1], b[1], acc[t][0], 0, 0, 0);
        acc[t][1] = __builtin_amdgcn_mfma_f32_16x16x32_fp8_fp8(a1[0], b[0], acc[t][1], 0, 0, 0);
        acc[t][1] = __builtin_amdgcn_mfma_f32_16x16x32_fp8_fp8(a1[1], b[1], acc[t][1], 0, 0, 0);
      }
    }
    // fold: B scaled by 2048 -> acc = 2048*dot; s = fma(-2/2048, acc, w2)
    #pragma unroll
    for (int t = 0; t < 8; ++t) {
      int code = (w * 32 + P * 8 + t) * 16 + l15;
      float w2 = w2f[code];
      #pragma unroll
      for (int i = 0; i < 4; ++i) {
        ins3(ts[0][i], packsc(fmaf(-0.0009765625f, acc[t][0][i], w2), code));
        ins3(ts[1][i], packsc(fmaf(-0.0009765625f, acc[t][1][i], w2), code));
      }
    }
  }

  __syncthreads();   // als dead; smem becomes candU

  // ---- Phase C: dump 192 candidates/row, two-stage merge -> top-8 codes
  #pragma unroll
  for (int rs = 0; rs < 2; ++rs)
    #pragma unroll
    for (int i = 0; i < 4; ++i) {
      int row = rs * 16 + q * 4 + i;
      #pragma unroll
      for (int j = 0; j < 3; ++j)
        candU[row * 192 + w * 48 + l15 * 3 + j] = ts[rs][i][j];
    }
  __syncthreads();

  {
    int row = tid >> 3, sl = tid & 7;
    unsigned int s8[8];
    #pragma unroll
    for (int k = 0; k < 8; ++k) s8[k] = 0xFFFFFFFFu;
    for (int e = 0; e < 24; ++e) {
      unsigned int v = candU[row * 192 + sl * 24 + e];
      if (v < s8[7]) {
        s8[7] = v;
        #pragma unroll
        for (int k = 7; k >= 1; --k)
          if (s8[k] < s8[k - 1]) { unsigned int t = s8[k-1]; s8[k-1] = s8[k]; s8[k] = t; }
      }
    }
    #pragma unroll
    for (int k = 0; k < 8; ++k) ps8[row][sl][k] = s8[k];
  }
  __syncthreads();

  if (tid < 32) {
    unsigned int s8[8];
    #pragma unroll
    for (int k = 0; k < 8; ++k) s8[k] = 0xFFFFFFFFu;
    const unsigned int* src = &ps8[tid][0][0];
    for (int e = 0; e < 64; ++e) {
      unsigned int v = src[e];
      if (v < s8[7]) {
        s8[7] = v;
        #pragma unroll
        for (int k = 7; k >= 1; --k)
          if (s8[k] < s8[k - 1]) { unsigned int t = s8[k-1]; s8[k-1] = s8[k]; s8[k] = t; }
      }
    }
    #pragma unroll
    for (int k = 0; k < 8; ++k)
      top8g[(size_t)(n0 + tid) * 8 + k] = (int)(s8[k] & 0x7FFu);
  }
}

// ---------------- k_refine: one wave per row; exact fp64 re-score of the 8
// coarse candidates; emits monotone-packed (score,code) keys.
__global__ __launch_bounds__(256, 4) void k_refine(
    const float* __restrict__ xt, const float* __restrict__ W,
    const double* __restrict__ w2d, const int* __restrict__ top8g,
    u64* __restrict__ cand)
{
  const int tid = threadIdx.x, w = tid >> 6, lane = tid & 63;
  const int n = blockIdx.x * 4 + w;
  const int c = lane >> 3, g = lane & 7;
  int code = top8g[(size_t)n * 8 + c];
  const float4* wp = (const float4*)(W  + (size_t)code * 512 + g * 64);
  const float4* xp = (const float4*)(xt + (size_t)n    * 512 + g * 64);
  double d0 = 0.0, d1 = 0.0, d2 = 0.0, d3 = 0.0;
  #pragma unroll
  for (int i = 0; i < 16; ++i) {
    float4 wv = wp[i];
    float4 xv = xp[i];
    d0 = fma((double)xv.x, (double)wv.x, d0);
    d1 = fma((double)xv.y, (double)wv.y, d1);
    d2 = fma((double)xv.z, (double)wv.z, d2);
    d3 = fma((double)xv.w, (double)wv.w, d3);
  }
  double dot = (d0 + d1) + (d2 + d3);
  dot += __shfl_xor(dot, 1);
  dot += __shfl_xor(dot, 2);
  dot += __shfl_xor(dot, 4);
  if (g == 0) {
    double s = w2d[code] - 2.0 * dot;
    cand[(size_t)n * 8 + c] = packsc64(s, code);
  }
}

// ---------------- k_merge: per row, top-3 of 8 fp64 keys -> idx/counts
__global__ __launch_bounds__(256) void k_merge(
    const u64* __restrict__ cand, int4* __restrict__ idx3,
    int* __restrict__ counts, float* __restrict__ out)
{
  int n = blockIdx.x * 256 + threadIdx.x;
  const u64* cp = cand + (size_t)n * 8;
  u64 k0 = ~0ull, k1 = ~0ull, k2 = ~0ull;
  #pragma unroll
  for (int e = 0; e < 8; ++e) {
    u64 v = cp[e];
    if (v < k2) {
      k2 = v;
      if (k2 < k1) { u64 t = k1; k1 = k2; k2 = t; }
      if (k1 < k0) { u64 t = k0; k0 = k1; k1 = t; }
    }
  }
  int c0 = (int)(k0 & 0x7FF), c1 = (int)(k1 & 0x7FF), c2 = (int)(k2 & 0x7FF);
  idx3[n] = make_int4(c0, c1, c2, 0);
  out[OUT_IDX_OFF + n] = (float)c2;
  atomicAdd(&counts[c0], 1);
  atomicAdd(&counts[c1], 1);
  atomicAdd(&counts[c2], 1);
}

// ---------------- k_qe: quantize + straight-through + fused loss (16 rows/block)
// Reads ORIGINAL x (xt region gets overwritten by q here).
__global__ __launch_bounds__(256) void k_qe(
    const float* __restrict__ x, const float* __restrict__ W,
    const int4* __restrict__ idx3, float* __restrict__ out,
    float* __restrict__ loss_acc)
{
  __shared__ float lred[4];
  const int tid = threadIdx.x;
  const int lane = tid & 63;
  const int n0 = blockIdx.x * 16;
  const int b  = n0 >> 8;
  const int t0 = n0 & 255;
  const int rr = tid & 15;
  const int g  = tid >> 4;             // 16 d-groups of 32 dims

  int4 ii = idx3[n0 + rr];
  const float4* w0 = (const float4*)(W + (size_t)ii.x * DIM);
  const float4* w1 = (const float4*)(W + (size_t)ii.y * DIM);
  const float4* w2 = (const float4*)(W + (size_t)ii.z * DIM);
  const float*  xr = x + (size_t)b * 131072 + t0 + rr;
  float* outq = out + OUT_Q_OFF + (size_t)b * 131072 + t0 + rr;
  float lsum = 0.0f;
  #pragma unroll
  for (int d4 = 0; d4 < 8; ++d4) {
    int idx4 = g * 8 + d4;
    float4 a0 = w0[idx4], a1 = w1[idx4], a2 = w2[idx4];
    float qv[4] = { (a0.x + a1.x + a2.x) * (1.0f/3.0f),
                    (a0.y + a1.y + a2.y) * (1.0f/3.0f),
                    (a0.z + a1.z + a2.z) * (1.0f/3.0f),
                    (a0.w + a1.w + a2.w) * (1.0f/3.0f) };
    #pragma unroll
    for (int e = 0; e < 4; ++e) {
      size_t off = (size_t)(idx4 * 4 + e) * 256;
      float xv = xr[off];
      float diff = qv[e] - xv;             // quantized - inp
      outq[off] = xv + diff;               // straight-through value
      lsum += diff * diff;
    }
  }
  for (int o = 32; o > 0; o >>= 1) lsum += __shfl_down(lsum, o);
  if (lane == 0) lred[tid >> 6] = lsum;
  __syncthreads();
  if (tid == 0)
    atomicAdd(loss_acc, (lred[0] + lred[1]) + (lred[2] + lred[3]));
}

// ---------------- k_final: loss + perplexity
__global__ __launch_bounds__(256) void k_final(
    const int* __restrict__ counts, const float* __restrict__ loss_acc,
    float* __restrict__ out)
{
  int tid = threadIdx.x;
  float ent = 0.0f;
  for (int k = tid; k < KC; k += 256) {
    float p = (float)counts[k] * (1.0f / 16384.0f);
    ent += p * logf(p + 1e-10f);
  }
  for (int o = 32; o > 0; o >>= 1) ent += __shfl_down(ent, o);
  __shared__ float ps[4];
  if ((tid & 63) == 0) ps[tid >> 6] = ent;
  __syncthreads();
  if (tid == 0) {
    float total = (ps[0] + ps[1]) + (ps[2] + ps[3]);
    out[0] = 1.25f * loss_acc[0] * (1.0f / 8388608.0f);  // q + 0.25*e latent
    out[OUT_P_OFF] = expf(-total);
  }
}

extern "C" void kernel_launch(void* const* d_in, const int* in_sizes, int n_in,
                              void* d_out, int out_size, void* d_ws, size_t ws_size,
                              hipStream_t stream) {
  const float* x = (const float*)d_in[0];
  const float* W = (const float*)d_in[1];
  float* out = (float*)d_out;
  char* ws = (char*)d_ws;
  int*           counts   = (int*)(ws + WS_COUNTS);
  float*         loss_acc = (float*)(ws + WS_LOSS);
  double*        w2d      = (double*)(ws + WS_W2D);
  float*         w2f      = (float*)(ws + WS_W2F);
  int4*          idx3     = (int4*)(ws + WS_IDX3);
  int*           top8g    = (int*)(ws + WS_TOP8);
  u64*           cand     = (u64*)(ws + WS_CAND);
  unsigned char* Wb       = (unsigned char*)(ws + WS_WB);
  float*         xt       = out + XT_OFF;     // scratch inside d_out

  hipMemsetAsync(ws, 0, 8448, stream);   // counts + loss accumulator
  k_prep<<<KC / 4, 256, 0, stream>>>(W, w2d, w2f, Wb);
  k_xt<<<dim3(DIM / 64, NROWS / 64), 256, 0, stream>>>(x, xt);
  k_score<<<NROWS / 32, 256, 0, stream>>>(xt, Wb, w2f, top8g);
  k_refine<<<NROWS / 4, 256, 0, stream>>>(xt, W, w2d, top8g, cand);
  k_merge<<<NROWS / 256, 256, 0, stream>>>(cand, idx3, counts, out);
  k_qe<<<NROWS / 16, 256, 0, stream>>>(x, W, idx3, out, loss_acc);
  k_final<<<1, 256, 0, stream>>>(counts, loss_acc, out);
}